// Round 3
// baseline (186.745 us; speedup 1.0000x reference)
//
#include <hip/hip_runtime.h>
#include <hip/hip_bf16.h>

#define HCn 4
#define Cn 2048
#define Dn (HCn*Cn)       // 8192
#define NLg 24            // HC*HC + 2*HC
#define TMAXn 8

typedef short bf16x8 __attribute__((ext_vector_type(8)));
typedef float f32x4 __attribute__((ext_vector_type(4)));

__device__ __forceinline__ unsigned int pk2(float a, float b) {
  union { __hip_bfloat162 h; unsigned int u; } v;
  v.h = __float22bfloat162_rn(float2{a, b});
  return v.u;
}
__device__ __forceinline__ float sigm(float z) { return 1.0f / (1.0f + expf(-z)); }

__device__ __forceinline__ void gload_lds16(const void* g, void* l) {
  __builtin_amdgcn_global_load_lds((__attribute__((address_space(1))) void*)(g),
                                   (__attribute__((address_space(3))) void*)(l),
                                   16, 0, 0);
}

// ---------------- Kernel 0: phi [8192][24] -> phiB B-fragment layout (bf16) ----------
// frag(ks, nt): k = ks*32 + (lane>>4)*8 + e, col = nt*16 + (lane&15)
// phiB[((ks*2+nt)*64 + lane)*8 + e]
__global__ __launch_bounds__(128) void phib_kernel(const float* __restrict__ phi,
                                                   unsigned short* __restrict__ phiB) {
  int tid = threadIdx.x;
  int nt = tid >> 6, lane = tid & 63;
  int ks = blockIdx.x;
  int col = nt * 16 + (lane & 15);
  int kb = ks * 32 + (lane >> 4) * 8;
  float v[8];
#pragma unroll
  for (int e = 0; e < 8; ++e)
    v[e] = (col < NLg) ? phi[(size_t)(kb + e) * NLg + col] : 0.f;
  uint4 o = { pk2(v[0], v[1]), pk2(v[2], v[3]), pk2(v[4], v[5]), pk2(v[6], v[7]) };
  *(uint4*)&phiB[((size_t)(ks * 2 + nt) * 64 + lane) * 8] = o;
}

// ---------------- Kernel 1: coeffs via MFMA + x_in (16 tokens/block, 8 waves K-split) --
__global__ __launch_bounds__(512) void coeffs_kernel(
    const float* __restrict__ x, const unsigned short* __restrict__ phiB,
    const float* __restrict__ bb, const float* __restrict__ apre_p,
    const float* __restrict__ apost_p, const float* __restrict__ ares_p,
    unsigned int* __restrict__ xin, float* __restrict__ hpost, float* __restrict__ hres) {
  __shared__ __align__(16) unsigned short As[8][2][1024];  // per-wave dbuf [16 tok][64 k]
  __shared__ float lgp[8][16][33];
  __shared__ float ssp[8][16];
  __shared__ float hpre_s[16][HCn];

  int tid = threadIdx.x, lane = tid & 63, wid = tid >> 6;
  long t0 = (long)blockIdx.x * 16;
  const float* xblk = x + (size_t)t0 * Dn;

  // staging: lane -> row=lane>>2 (token), k-chunk (lane&3)*16 within wave K-window
  int srow = lane >> 2;
  const float* xw = xblk + (size_t)srow * Dn + wid * 1024 + (lane & 3) * 16;
  int wb0 = srow * 128 + (((lane & 3) * 32) ^ ((srow & 7) << 4));
  int wb1 = srow * 128 + (((lane & 3) * 32 + 16) ^ ((srow & 7) << 4));
  // A-frag read: row = lane&15, kbyte = ksub*64 + (lane>>4)*16, XOR-swizzled
  int rrow = lane & 15;
  int rb0 = rrow * 128 + (((lane >> 4) * 16) ^ ((rrow & 7) << 4));
  int rb1 = rrow * 128 + ((64 + (lane >> 4) * 16) ^ ((rrow & 7) << 4));

  const bf16x8* pB0 = (const bf16x8*)phiB + (size_t)wid * 4096 + lane;  // wave K-window base

  float ss = 0.f;
  f32x4 acc0 = {0.f, 0.f, 0.f, 0.f}, acc1 = {0.f, 0.f, 0.f, 0.f};

#define LOADB(IT, B) { int j2 = (IT) * 2;                 \
    B[0] = pB0[(j2 * 2 + 0) * 64];                        \
    B[1] = pB0[(j2 * 2 + 1) * 64];                        \
    B[2] = pB0[((j2 + 1) * 2 + 0) * 64];                  \
    B[3] = pB0[((j2 + 1) * 2 + 1) * 64]; }

#define STAGE(IT, BUF) {                                                      \
    const float4* sp_ = (const float4*)(xw + (IT) * 64);                      \
    float4 v0 = sp_[0], v1 = sp_[1], v2 = sp_[2], v3 = sp_[3];                \
    ss += v0.x*v0.x + v0.y*v0.y + v0.z*v0.z + v0.w*v0.w;                      \
    ss += v1.x*v1.x + v1.y*v1.y + v1.z*v1.z + v1.w*v1.w;                      \
    ss += v2.x*v2.x + v2.y*v2.y + v2.z*v2.z + v2.w*v2.w;                      \
    ss += v3.x*v3.x + v3.y*v3.y + v3.z*v3.z + v3.w*v3.w;                      \
    uint4 lo = { pk2(v0.x,v0.y), pk2(v0.z,v0.w), pk2(v1.x,v1.y), pk2(v1.z,v1.w) }; \
    uint4 hi = { pk2(v2.x,v2.y), pk2(v2.z,v2.w), pk2(v3.x,v3.y), pk2(v3.z,v3.w) }; \
    *(uint4*)((char*)(BUF) + wb0) = lo;                                       \
    *(uint4*)((char*)(BUF) + wb1) = hi; }

#define MFMASTEP(BUF, B) {                                                    \
    bf16x8 a0 = *(const bf16x8*)((char*)(BUF) + rb0);                         \
    bf16x8 a1 = *(const bf16x8*)((char*)(BUF) + rb1);                         \
    acc0 = __builtin_amdgcn_mfma_f32_16x16x32_bf16(a0, B[0], acc0, 0, 0, 0);  \
    acc1 = __builtin_amdgcn_mfma_f32_16x16x32_bf16(a0, B[1], acc1, 0, 0, 0);  \
    acc0 = __builtin_amdgcn_mfma_f32_16x16x32_bf16(a1, B[2], acc0, 0, 0, 0);  \
    acc1 = __builtin_amdgcn_mfma_f32_16x16x32_bf16(a1, B[3], acc1, 0, 0, 0); }

  unsigned short* A0 = &As[wid][0][0];
  unsigned short* A1 = &As[wid][1][0];
  bf16x8 bA[4], bB[4];
  LOADB(0, bA); STAGE(0, A0);
#pragma unroll
  for (int ii = 0; ii < 8; ++ii) {
    LOADB(ii * 2 + 1, bB); STAGE(ii * 2 + 1, A1);
    MFMASTEP(A0, bA);
    if (ii < 7) { LOADB(ii * 2 + 2, bA); STAGE(ii * 2 + 2, A0); }
    MFMASTEP(A1, bB);
  }
#undef LOADB
#undef STAGE
#undef MFMASTEP

  // ss partial: 4 lanes per token row
  ss += __shfl_xor(ss, 1); ss += __shfl_xor(ss, 2);
  if ((lane & 3) == 0) ssp[wid][srow] = ss;
  // partial logits -> LDS (C layout: col=lane&15, row=(lane>>4)*4+e)
#pragma unroll
  for (int e = 0; e < 4; ++e) {
    int row = (lane >> 4) * 4 + e;
    lgp[wid][row][lane & 15] = acc0[e];
    lgp[wid][row][16 + (lane & 15)] = acc1[e];
  }
  __syncthreads();

  if (tid < 16) {
    long t = t0 + tid;
    float st = 0.f;
#pragma unroll
    for (int w = 0; w < 8; ++w) st += ssp[w][tid];
    float r = rsqrtf(st / (float)Dn + 1e-6f);
    float apre = apre_p[0], apost = apost_p[0], ares = ares_p[0];
    float lg[NLg];
#pragma unroll
    for (int j = 0; j < NLg; ++j) {
      float d = 0.f;
#pragma unroll
      for (int w = 0; w < 8; ++w) d += lgp[w][tid][j];
      lg[j] = r * d + bb[j];
    }
#pragma unroll
    for (int j = 0; j < 4; ++j) hpre_s[tid][j] = sigm(apre * lg[j]) + 1e-4f;
#pragma unroll
    for (int j = 0; j < 4; ++j) hpost[t * 4 + j] = 2.0f * sigm(apost * lg[4 + j]);
    float m[16];
#pragma unroll
    for (int q = 0; q < 16; ++q) m[q] = expf(ares * lg[8 + q]);
    for (int it = 0; it < TMAXn; ++it) {
#pragma unroll
      for (int o = 0; o < 4; ++o) {
        float rs = m[o*4] + m[o*4+1] + m[o*4+2] + m[o*4+3] + 1e-6f;
        m[o*4] /= rs; m[o*4+1] /= rs; m[o*4+2] /= rs; m[o*4+3] /= rs;
      }
#pragma unroll
      for (int i = 0; i < 4; ++i) {
        float cs = m[i] + m[4+i] + m[8+i] + m[12+i] + 1e-6f;
        m[i] /= cs; m[4+i] /= cs; m[8+i] /= cs; m[12+i] /= cs;
      }
    }
#pragma unroll
    for (int q = 0; q < 16; ++q) hres[t * 16 + q] = m[q];
  }
  __syncthreads();

  // phase 2: x_in (bf16) — 32 threads per token
  int t = tid >> 5, l32 = tid & 31;
  const float4* xt = (const float4*)(xblk + (size_t)t * Dn);
  float h0 = hpre_s[t][0], h1 = hpre_s[t][1], h2 = hpre_s[t][2], h3 = hpre_s[t][3];
  uint2* xo = (uint2*)xin + (size_t)(t0 + t) * (Cn / 4);
#pragma unroll
  for (int itc = 0; itc < 16; ++itc) {
    int c4 = itc * 32 + l32;
    float4 v0 = xt[c4];
    float4 v1 = xt[c4 + 512];
    float4 v2 = xt[c4 + 1024];
    float4 v3 = xt[c4 + 1536];
    float sx = h0*v0.x + h1*v1.x + h2*v2.x + h3*v3.x;
    float sy = h0*v0.y + h1*v1.y + h2*v2.y + h3*v3.y;
    float sz = h0*v0.z + h1*v1.z + h2*v2.z + h3*v3.z;
    float sw = h0*v0.w + h1*v1.w + h2*v2.w + h3*v3.w;
    uint2 o; o.x = pk2(sx, sy); o.y = pk2(sz, sw);
    xo[c4] = o;
  }
}

// ---------------- Kernel 2: W (K x N, f32) -> Wt (N x K, bf16) ----------------
__global__ __launch_bounds__(256) void wtrans_kernel(const float* __restrict__ W,
                                                     unsigned short* __restrict__ Wt) {
  __shared__ float tile[64][65];
  int kb = blockIdx.y * 64, nb = blockIdx.x * 64;
  int tr = threadIdx.x >> 4;
  int tc = threadIdx.x & 15;
#pragma unroll
  for (int rr = 0; rr < 64; rr += 16) {
    float4 v = *(const float4*)&W[(size_t)(kb + tr + rr) * Cn + nb + tc * 4];
    tile[tr + rr][tc * 4 + 0] = v.x; tile[tr + rr][tc * 4 + 1] = v.y;
    tile[tr + rr][tc * 4 + 2] = v.z; tile[tr + rr][tc * 4 + 3] = v.w;
  }
  __syncthreads();
#pragma unroll
  for (int rr = 0; rr < 64; rr += 16) {
    int n = nb + tr + rr;
    uint2 o;
    o.x = pk2(tile[tc * 4 + 0][tr + rr], tile[tc * 4 + 1][tr + rr]);
    o.y = pk2(tile[tc * 4 + 2][tr + rr], tile[tc * 4 + 3][tr + rr]);
    *(uint2*)&Wt[(size_t)n * Cn + kb + tc * 4] = o;
  }
}

// ---------------- Kernel 3: bf16 MFMA GEMM (x_in @ W) + fused epilogue ----------------
#define BMt 128
#define BNt 128
#define BKt 32
#define GK Cn
__global__ __launch_bounds__(256) void gemm_ep_kernel(
    const unsigned short* __restrict__ xin, const unsigned short* __restrict__ Wt,
    const float* __restrict__ x, const float* __restrict__ Wb,
    const float* __restrict__ hpost, const float* __restrict__ hres,
    float* __restrict__ out) {
  __shared__ __align__(16) unsigned short As[BMt * BKt];
  __shared__ __align__(16) unsigned short Bs[BNt * BKt];
  int tid = threadIdx.x;
  int lane = tid & 63, wid = tid >> 6;
  int wr = wid >> 1, wc = wid & 1;
  int l15 = lane & 15, l4 = lane >> 4;
  int bx = blockIdx.x, by = blockIdx.y;

  f32x4 acc[4][4];
#pragma unroll
  for (int i = 0; i < 4; ++i)
#pragma unroll
    for (int j = 0; j < 4; ++j) acc[i][j] = {0.f, 0.f, 0.f, 0.f};

  const char* Ab = (const char*)xin + (size_t)by * BMt * GK * 2;
  const char* Bb = (const char*)Wt + (size_t)bx * BNt * GK * 2;
  int off0 = tid * 16, off1 = tid * 16 + 4096;
  int row0 = off0 >> 6, colb0 = off0 & 63;
  int row1 = off1 >> 6, colb1 = off1 & 63;

  for (int k0 = 0; k0 < GK; k0 += BKt) {
    gload_lds16(Ab + (size_t)row0 * (GK * 2) + k0 * 2 + colb0, (char*)As + off0);
    gload_lds16(Ab + (size_t)row1 * (GK * 2) + k0 * 2 + colb1, (char*)As + off1);
    gload_lds16(Bb + (size_t)row0 * (GK * 2) + k0 * 2 + colb0, (char*)Bs + off0);
    gload_lds16(Bb + (size_t)row1 * (GK * 2) + k0 * 2 + colb1, (char*)Bs + off1);
    __syncthreads();
    bf16x8 af[4], bfv[4];
#pragma unroll
    for (int fm = 0; fm < 4; ++fm)
      af[fm] = *(const bf16x8*)&As[(wr * 64 + fm * 16 + l15) * BKt + l4 * 8];
#pragma unroll
    for (int fn = 0; fn < 4; ++fn)
      bfv[fn] = *(const bf16x8*)&Bs[(wc * 64 + fn * 16 + l15) * BKt + l4 * 8];
#pragma unroll
    for (int fm = 0; fm < 4; ++fm)
#pragma unroll
      for (int fn = 0; fn < 4; ++fn)
        acc[fm][fn] = __builtin_amdgcn_mfma_f32_16x16x32_bf16(af[fm], bfv[fn], acc[fm][fn], 0, 0, 0);
    __syncthreads();
  }

  int m0 = by * BMt + wr * 64;
  int n0 = bx * BNt + wc * 64;
#pragma unroll
  for (int fm = 0; fm < 4; ++fm) {
#pragma unroll
    for (int e = 0; e < 4; ++e) {
      int t = m0 + fm * 16 + l4 * 4 + e;
      const float* hr = hres + (size_t)t * 16;
      const float* hq = hpost + (size_t)t * 4;
      const float* xt = x + (size_t)t * Dn;
      float* ot = out + (size_t)t * Dn;
      float hr_[16], hq_[4];
#pragma unroll
      for (int q = 0; q < 16; ++q) hr_[q] = hr[q];
#pragma unroll
      for (int q = 0; q < 4; ++q) hq_[q] = hq[q];
#pragma unroll
      for (int fn = 0; fn < 4; ++fn) {
        int c = n0 + fn * 16 + l15;
        float f = acc[fm][fn][e] + Wb[c];
        float x0 = xt[c], x1 = xt[Cn + c], x2 = xt[2 * Cn + c], x3 = xt[3 * Cn + c];
#pragma unroll
        for (int o = 0; o < 4; ++o) {
          ot[(size_t)o * Cn + c] =
              hq_[o] * f + hr_[o*4+0] * x0 + hr_[o*4+1] * x1 + hr_[o*4+2] * x2 + hr_[o*4+3] * x3;
        }
      }
    }
  }
}

extern "C" void kernel_launch(void* const* d_in, const int* in_sizes, int n_in,
                              void* d_out, int out_size, void* d_ws, size_t ws_size,
                              hipStream_t stream) {
  const float* x     = (const float*)d_in[0];
  const float* phi   = (const float*)d_in[1];
  const float* b     = (const float*)d_in[2];
  const float* apre  = (const float*)d_in[3];
  const float* apost = (const float*)d_in[4];
  const float* ares  = (const float*)d_in[5];
  const float* W     = (const float*)d_in[6];
  const float* Wb    = (const float*)d_in[7];
  float* out = (float*)d_out;

  int NT = in_sizes[0] / Dn;   // 4096 tokens
  char* ws = (char*)d_ws;
  size_t xin_b = (size_t)NT * Cn * 2;        // 16 MB
  size_t wt_b  = (size_t)Cn * Cn * 2;        // 8 MB
  size_t hp_b  = (size_t)NT * 4 * 4;
  size_t hr_b  = (size_t)NT * 16 * 4;
  unsigned int*   xin  = (unsigned int*)ws;
  unsigned short* Wt   = (unsigned short*)(ws + xin_b);
  float* hpost = (float*)(ws + xin_b + wt_b);
  float* hres  = (float*)(ws + xin_b + wt_b + hp_b);
  unsigned short* phiB = (unsigned short*)(ws + xin_b + wt_b + hp_b + hr_b);

  hipLaunchKernelGGL(phib_kernel, dim3(Dn / 32), dim3(128), 0, stream, phi, phiB);
  hipLaunchKernelGGL(coeffs_kernel, dim3(NT / 16), dim3(512), 0, stream,
                     x, phiB, b, apre, apost, ares, xin, hpost, hres);
  hipLaunchKernelGGL(wtrans_kernel, dim3(Cn / 64, Cn / 64), dim3(256), 0, stream, W, Wt);
  hipLaunchKernelGGL(gemm_ep_kernel, dim3(Cn / BNt, NT / BMt), dim3(256), 0, stream,
                     (const unsigned short*)xin, Wt, x, Wb, hpost, hres, out);
}

// Round 4
// 177.827 us; speedup vs baseline: 1.0502x; 1.0502x over previous
//
#include <hip/hip_runtime.h>
#include <hip/hip_bf16.h>

#define HCn 4
#define Cn 2048
#define Dn (HCn*Cn)       // 8192
#define NLg 24            // HC*HC + 2*HC
#define TMAXn 8

typedef short bf16x8 __attribute__((ext_vector_type(8)));
typedef float f32x4 __attribute__((ext_vector_type(4)));

__device__ __forceinline__ unsigned int pk2(float a, float b) {
  union { __hip_bfloat162 h; unsigned int u; } v;
  v.h = __float22bfloat162_rn(float2{a, b});
  return v.u;
}
__device__ __forceinline__ float sigm(float z) { return 1.0f / (1.0f + expf(-z)); }

__device__ __forceinline__ void gload_lds16(const void* g, void* l) {
  __builtin_amdgcn_global_load_lds((__attribute__((address_space(1))) void*)(g),
                                   (__attribute__((address_space(3))) void*)(l),
                                   16, 0, 0);
}

// ---------------- Kernel 0: phi [8192][24] -> phiB B-fragment layout (bf16) ----------
// frag(ks, nt): k = ks*32 + (lane>>4)*8 + e, col = nt*16 + (lane&15)
__global__ __launch_bounds__(128) void phib_kernel(const float* __restrict__ phi,
                                                   unsigned short* __restrict__ phiB) {
  int tid = threadIdx.x;
  int nt = tid >> 6, lane = tid & 63;
  int ks = blockIdx.x;
  int col = nt * 16 + (lane & 15);
  int kb = ks * 32 + (lane >> 4) * 8;
  float v[8];
#pragma unroll
  for (int e = 0; e < 8; ++e)
    v[e] = (col < NLg) ? phi[(size_t)(kb + e) * NLg + col] : 0.f;
  uint4 o = { pk2(v[0], v[1]), pk2(v[2], v[3]), pk2(v[4], v[5]), pk2(v[6], v[7]) };
  *(uint4*)&phiB[((size_t)(ks * 2 + nt) * 64 + lane) * 8] = o;
}

// ------- Kernel 1: coeffs via reg-direct MFMA + x_in (16 tok/block, 8 waves K-split) --
__global__ __launch_bounds__(512) void coeffs_kernel(
    const float* __restrict__ x, const unsigned short* __restrict__ phiB,
    const float* __restrict__ bb, const float* __restrict__ apre_p,
    const float* __restrict__ apost_p, const float* __restrict__ ares_p,
    unsigned int* __restrict__ xin, float* __restrict__ hpost, float* __restrict__ hres) {
  __shared__ float lgp[8][16][33];
  __shared__ float ssp[8][16];
  __shared__ float hpre_s[16][HCn];

  int tid = threadIdx.x, lane = tid & 63, wid = tid >> 6;
  long t0 = (long)blockIdx.x * 16;
  const float* xblk = x + (size_t)t0 * Dn;

  int l15 = lane & 15, kg = lane >> 4;
  // A: row (token) = l15, k = wid*1024 + it*32 + kg*8 + e  -> 2x float4 per it
  const float* xr = xblk + (size_t)l15 * Dn + wid * 1024 + kg * 8;
  const bf16x8* pB = (const bf16x8*)phiB + (size_t)wid * 32 * 128 + lane;

  float ss = 0.f;
  f32x4 acc0 = {0.f,0.f,0.f,0.f}, acc1 = {0.f,0.f,0.f,0.f};

#define LOADIT(IT, P0, P1, B0, B1) {            \
    P0 = *(const float4*)(xr + (IT) * 32);      \
    P1 = *(const float4*)(xr + (IT) * 32 + 4);  \
    B0 = pB[(IT) * 128];                        \
    B1 = pB[(IT) * 128 + 64]; }

#define PROCIT(P0, P1, B0, B1) {                                              \
    ss += P0.x*P0.x + P0.y*P0.y + P0.z*P0.z + P0.w*P0.w;                      \
    ss += P1.x*P1.x + P1.y*P1.y + P1.z*P1.z + P1.w*P1.w;                      \
    uint4 u_ = { pk2(P0.x,P0.y), pk2(P0.z,P0.w), pk2(P1.x,P1.y), pk2(P1.z,P1.w) }; \
    bf16x8 a_ = *(bf16x8*)&u_;                                                \
    acc0 = __builtin_amdgcn_mfma_f32_16x16x32_bf16(a_, B0, acc0, 0, 0, 0);    \
    acc1 = __builtin_amdgcn_mfma_f32_16x16x32_bf16(a_, B1, acc1, 0, 0, 0); }

  {
    float4 pA0, pA1, qA0, qA1; bf16x8 bA0, bA1, bB0, bB1;
    LOADIT(0, pA0, pA1, bA0, bA1);
#pragma unroll
    for (int it = 0; it < 32; it += 2) {
      LOADIT(it + 1, qA0, qA1, bB0, bB1);
      PROCIT(pA0, pA1, bA0, bA1);
      if (it + 2 < 32) LOADIT(it + 2, pA0, pA1, bA0, bA1);
      PROCIT(qA0, qA1, bB0, bB1);
    }
  }
#undef LOADIT
#undef PROCIT

  // ss: lanes {l15, l15+16, l15+32, l15+48} hold partials for token l15
  ss += __shfl_xor(ss, 16); ss += __shfl_xor(ss, 32);
  if (kg == 0) ssp[wid][l15] = ss;
  // C layout: j = l15 (acc0) / 16+l15 (acc1), token = kg*4+e
#pragma unroll
  for (int e = 0; e < 4; ++e) {
    int tok = kg * 4 + e;
    lgp[wid][tok][l15] = acc0[e];
    lgp[wid][tok][16 + l15] = acc1[e];
  }
  __syncthreads();

  if (tid < 16) {
    long t = t0 + tid;
    float st = 0.f;
#pragma unroll
    for (int w = 0; w < 8; ++w) st += ssp[w][tid];
    float r = rsqrtf(st / (float)Dn + 1e-6f);
    float apre = apre_p[0], apost = apost_p[0], ares = ares_p[0];
    float lg[NLg];
#pragma unroll
    for (int j = 0; j < NLg; ++j) {
      float d = 0.f;
#pragma unroll
      for (int w = 0; w < 8; ++w) d += lgp[w][tid][j];
      lg[j] = r * d + bb[j];
    }
#pragma unroll
    for (int j = 0; j < 4; ++j) hpre_s[tid][j] = sigm(apre * lg[j]) + 1e-4f;
#pragma unroll
    for (int j = 0; j < 4; ++j) hpost[t * 4 + j] = 2.0f * sigm(apost * lg[4 + j]);
    float m[16];
#pragma unroll
    for (int q = 0; q < 16; ++q) m[q] = expf(ares * lg[8 + q]);
    for (int it = 0; it < TMAXn; ++it) {
#pragma unroll
      for (int o = 0; o < 4; ++o) {
        float rs = m[o*4] + m[o*4+1] + m[o*4+2] + m[o*4+3] + 1e-6f;
        m[o*4] /= rs; m[o*4+1] /= rs; m[o*4+2] /= rs; m[o*4+3] /= rs;
      }
#pragma unroll
      for (int i = 0; i < 4; ++i) {
        float cs = m[i] + m[4+i] + m[8+i] + m[12+i] + 1e-6f;
        m[i] /= cs; m[4+i] /= cs; m[8+i] /= cs; m[12+i] /= cs;
      }
    }
#pragma unroll
    for (int q = 0; q < 16; ++q) hres[t * 16 + q] = m[q];
  }
  __syncthreads();

  // phase 2: x_in (bf16) — 32 threads per token, strip is L2/L3-warm
  int t = tid >> 5, l32 = tid & 31;
  const float4* xt = (const float4*)(xblk + (size_t)t * Dn);
  float h0 = hpre_s[t][0], h1 = hpre_s[t][1], h2 = hpre_s[t][2], h3 = hpre_s[t][3];
  uint2* xo = (uint2*)xin + (size_t)(t0 + t) * (Cn / 4);
#pragma unroll
  for (int itc = 0; itc < 16; ++itc) {
    int c4 = itc * 32 + l32;
    float4 v0 = xt[c4];
    float4 v1 = xt[c4 + 512];
    float4 v2 = xt[c4 + 1024];
    float4 v3 = xt[c4 + 1536];
    float sx = h0*v0.x + h1*v1.x + h2*v2.x + h3*v3.x;
    float sy = h0*v0.y + h1*v1.y + h2*v2.y + h3*v3.y;
    float sz = h0*v0.z + h1*v1.z + h2*v2.z + h3*v3.z;
    float sw = h0*v0.w + h1*v1.w + h2*v2.w + h3*v3.w;
    uint2 o; o.x = pk2(sx, sy); o.y = pk2(sz, sw);
    xo[c4] = o;
  }
}

// ---------------- Kernel 2: W (K x N, f32) -> Wt (N x K, bf16) ----------------
__global__ __launch_bounds__(256) void wtrans_kernel(const float* __restrict__ W,
                                                     unsigned short* __restrict__ Wt) {
  __shared__ float tile[64][65];
  int kb = blockIdx.y * 64, nb = blockIdx.x * 64;
  int tr = threadIdx.x >> 4;
  int tc = threadIdx.x & 15;
#pragma unroll
  for (int rr = 0; rr < 64; rr += 16) {
    float4 v = *(const float4*)&W[(size_t)(kb + tr + rr) * Cn + nb + tc * 4];
    tile[tr + rr][tc * 4 + 0] = v.x; tile[tr + rr][tc * 4 + 1] = v.y;
    tile[tr + rr][tc * 4 + 2] = v.z; tile[tr + rr][tc * 4 + 3] = v.w;
  }
  __syncthreads();
#pragma unroll
  for (int rr = 0; rr < 64; rr += 16) {
    int n = nb + tr + rr;
    uint2 o;
    o.x = pk2(tile[tc * 4 + 0][tr + rr], tile[tc * 4 + 1][tr + rr]);
    o.y = pk2(tile[tc * 4 + 2][tr + rr], tile[tc * 4 + 3][tr + rr]);
    *(uint2*)&Wt[(size_t)n * Cn + kb + tc * 4] = o;
  }
}

// ---------------- Kernel 3: bf16 MFMA GEMM (x_in @ W) + fused epilogue ----------------
#define BMt 128
#define BNt 128
#define BKt 32
#define GK Cn
__global__ __launch_bounds__(256) void gemm_ep_kernel(
    const unsigned short* __restrict__ xin, const unsigned short* __restrict__ Wt,
    const float* __restrict__ x, const float* __restrict__ Wb,
    const float* __restrict__ hpost, const float* __restrict__ hres,
    float* __restrict__ out) {
  __shared__ __align__(16) unsigned short As[BMt * BKt];
  __shared__ __align__(16) unsigned short Bs[BNt * BKt];
  int tid = threadIdx.x;
  int lane = tid & 63, wid = tid >> 6;
  int wr = wid >> 1, wc = wid & 1;
  int l15 = lane & 15, l4 = lane >> 4;
  // 1D grid + XCD-aware swizzle (512 blocks, 512 % 8 == 0 -> bijective)
  int wg = blockIdx.x;
  wg = (wg & 7) * 64 + (wg >> 3);
  int bx = wg & 15, by = wg >> 4;

  f32x4 acc[4][4];
#pragma unroll
  for (int i = 0; i < 4; ++i)
#pragma unroll
    for (int j = 0; j < 4; ++j) acc[i][j] = {0.f, 0.f, 0.f, 0.f};

  const char* Ab = (const char*)xin + (size_t)by * BMt * GK * 2;
  const char* Bb = (const char*)Wt + (size_t)bx * BNt * GK * 2;
  int off0 = tid * 16, off1 = tid * 16 + 4096;
  int row0 = off0 >> 6, colb0 = off0 & 63;
  int row1 = off1 >> 6, colb1 = off1 & 63;

  for (int k0 = 0; k0 < GK; k0 += BKt) {
    gload_lds16(Ab + (size_t)row0 * (GK * 2) + k0 * 2 + colb0, (char*)As + off0);
    gload_lds16(Ab + (size_t)row1 * (GK * 2) + k0 * 2 + colb1, (char*)As + off1);
    gload_lds16(Bb + (size_t)row0 * (GK * 2) + k0 * 2 + colb0, (char*)Bs + off0);
    gload_lds16(Bb + (size_t)row1 * (GK * 2) + k0 * 2 + colb1, (char*)Bs + off1);
    __syncthreads();
    bf16x8 af[4], bfv[4];
#pragma unroll
    for (int fm = 0; fm < 4; ++fm)
      af[fm] = *(const bf16x8*)&As[(wr * 64 + fm * 16 + l15) * BKt + l4 * 8];
#pragma unroll
    for (int fn = 0; fn < 4; ++fn)
      bfv[fn] = *(const bf16x8*)&Bs[(wc * 64 + fn * 16 + l15) * BKt + l4 * 8];
#pragma unroll
    for (int fm = 0; fm < 4; ++fm)
#pragma unroll
      for (int fn = 0; fn < 4; ++fn)
        acc[fm][fn] = __builtin_amdgcn_mfma_f32_16x16x32_bf16(af[fm], bfv[fn], acc[fm][fn], 0, 0, 0);
    __syncthreads();
  }

  int m0 = by * BMt + wr * 64;
  int n0 = bx * BNt + wc * 64;
#pragma unroll
  for (int fm = 0; fm < 4; ++fm) {
#pragma unroll
    for (int e = 0; e < 4; ++e) {
      int t = m0 + fm * 16 + l4 * 4 + e;
      const float* hr = hres + (size_t)t * 16;
      const float* hq = hpost + (size_t)t * 4;
      const float* xt = x + (size_t)t * Dn;
      float* ot = out + (size_t)t * Dn;
      float hr_[16], hq_[4];
#pragma unroll
      for (int q = 0; q < 16; ++q) hr_[q] = hr[q];
#pragma unroll
      for (int q = 0; q < 4; ++q) hq_[q] = hq[q];
#pragma unroll
      for (int fn = 0; fn < 4; ++fn) {
        int c = n0 + fn * 16 + l15;
        float f = acc[fm][fn][e] + Wb[c];
        float x0 = xt[c], x1 = xt[Cn + c], x2 = xt[2 * Cn + c], x3 = xt[3 * Cn + c];
#pragma unroll
        for (int o = 0; o < 4; ++o) {
          ot[(size_t)o * Cn + c] =
              hq_[o] * f + hr_[o*4+0] * x0 + hr_[o*4+1] * x1 + hr_[o*4+2] * x2 + hr_[o*4+3] * x3;
        }
      }
    }
  }
}

extern "C" void kernel_launch(void* const* d_in, const int* in_sizes, int n_in,
                              void* d_out, int out_size, void* d_ws, size_t ws_size,
                              hipStream_t stream) {
  const float* x     = (const float*)d_in[0];
  const float* phi   = (const float*)d_in[1];
  const float* b     = (const float*)d_in[2];
  const float* apre  = (const float*)d_in[3];
  const float* apost = (const float*)d_in[4];
  const float* ares  = (const float*)d_in[5];
  const float* W     = (const float*)d_in[6];
  const float* Wb    = (const float*)d_in[7];
  float* out = (float*)d_out;

  int NT = in_sizes[0] / Dn;   // 4096 tokens
  char* ws = (char*)d_ws;
  size_t xin_b = (size_t)NT * Cn * 2;        // 16 MB
  size_t wt_b  = (size_t)Cn * Cn * 2;        // 8 MB
  size_t hp_b  = (size_t)NT * 4 * 4;
  size_t hr_b  = (size_t)NT * 16 * 4;
  unsigned int*   xin  = (unsigned int*)ws;
  unsigned short* Wt   = (unsigned short*)(ws + xin_b);
  float* hpost = (float*)(ws + xin_b + wt_b);
  float* hres  = (float*)(ws + xin_b + wt_b + hp_b);
  unsigned short* phiB = (unsigned short*)(ws + xin_b + wt_b + hp_b + hr_b);

  hipLaunchKernelGGL(phib_kernel, dim3(Dn / 32), dim3(128), 0, stream, phi, phiB);
  hipLaunchKernelGGL(coeffs_kernel, dim3(NT / 16), dim3(512), 0, stream,
                     x, phiB, b, apre, apost, ares, xin, hpost, hres);
  hipLaunchKernelGGL(wtrans_kernel, dim3(Cn / 64, Cn / 64), dim3(256), 0, stream, W, Wt);
  hipLaunchKernelGGL(gemm_ep_kernel, dim3((Cn / BNt) * (NT / BMt)), dim3(256), 0, stream,
                     (const unsigned short*)xin, Wt, x, Wb, hpost, hres, out);
}

// Round 5
// 164.261 us; speedup vs baseline: 1.1369x; 1.0826x over previous
//
#include <hip/hip_runtime.h>
#include <hip/hip_bf16.h>

#define HCn 4
#define Cn 2048
#define Dn (HCn*Cn)       // 8192
#define NLg 24            // HC*HC + 2*HC
#define TMAXn 8

typedef short bf16x8 __attribute__((ext_vector_type(8)));
typedef float f32x4 __attribute__((ext_vector_type(4)));

__device__ __forceinline__ unsigned int pk2(float a, float b) {
  union { __hip_bfloat162 h; unsigned int u; } v;
  v.h = __float22bfloat162_rn(float2{a, b});
  return v.u;
}
__device__ __forceinline__ float sigm(float z) { return 1.0f / (1.0f + expf(-z)); }

__device__ __forceinline__ void gload_lds16(const void* g, void* l) {
  __builtin_amdgcn_global_load_lds((__attribute__((address_space(1))) void*)(g),
                                   (__attribute__((address_space(3))) void*)(l),
                                   16, 0, 0);
}

// ---------------- Kernel 0: phi [8192][24] -> phiB B-fragment layout (bf16) ----------
__global__ __launch_bounds__(128) void phib_kernel(const float* __restrict__ phi,
                                                   unsigned short* __restrict__ phiB) {
  int tid = threadIdx.x;
  int nt = tid >> 6, lane = tid & 63;
  int ks = blockIdx.x;
  int col = nt * 16 + (lane & 15);
  int kb = ks * 32 + (lane >> 4) * 8;
  float v[8];
#pragma unroll
  for (int e = 0; e < 8; ++e)
    v[e] = (col < NLg) ? phi[(size_t)(kb + e) * NLg + col] : 0.f;
  uint4 o = { pk2(v[0], v[1]), pk2(v[2], v[3]), pk2(v[4], v[5]), pk2(v[6], v[7]) };
  *(uint4*)&phiB[((size_t)(ks * 2 + nt) * 64 + lane) * 8] = o;
}

// ------- Kernel 1: split-K logits partials. 1024 blocks = 256 tok-groups x 4 K-chunks.
// 512 thr = 8 waves; wave K-window = 256 (8 iters), lookahead-2 register pipeline.
__global__ __launch_bounds__(512) void logits_kernel(
    const float* __restrict__ x, const unsigned short* __restrict__ phiB,
    float* __restrict__ pbuf) {
  __shared__ float lgp[8][16][33];
  __shared__ float ssp[8][16];

  int tid = threadIdx.x, lane = tid & 63, wid = tid >> 6;
  int g = blockIdx.x >> 2;        // token group (16 tokens)
  int kc = blockIdx.x & 3;        // K-chunk (2048 wide)
  long t0 = (long)g * 16;
  int l15 = lane & 15, kg = lane >> 4;

  int kbase = kc * 2048 + wid * 256;
  const float* xr = x + (size_t)(t0 + l15) * Dn + kbase + kg * 8;
  const bf16x8* pB = (const bf16x8*)phiB + (size_t)(kbase >> 5) * 128 + lane;

  float ss = 0.f;
  f32x4 acc0 = {0.f,0.f,0.f,0.f}, acc1 = {0.f,0.f,0.f,0.f};

  float4 A0[3], A1[3]; bf16x8 Bv0[3], Bv1[3];
#define LOADIT(IT, S) {                          \
    A0[S] = *(const float4*)(xr + (IT) * 32);    \
    A1[S] = *(const float4*)(xr + (IT) * 32 + 4);\
    Bv0[S] = pB[(IT) * 128];                     \
    Bv1[S] = pB[(IT) * 128 + 64]; }
#define PROCIT(S) {                                                           \
    float4 P0 = A0[S], P1 = A1[S];                                            \
    ss += P0.x*P0.x + P0.y*P0.y + P0.z*P0.z + P0.w*P0.w;                      \
    ss += P1.x*P1.x + P1.y*P1.y + P1.z*P1.z + P1.w*P1.w;                      \
    uint4 u_ = { pk2(P0.x,P0.y), pk2(P0.z,P0.w), pk2(P1.x,P1.y), pk2(P1.z,P1.w) }; \
    bf16x8 a_ = *(bf16x8*)&u_;                                                \
    acc0 = __builtin_amdgcn_mfma_f32_16x16x32_bf16(a_, Bv0[S], acc0, 0, 0, 0);\
    acc1 = __builtin_amdgcn_mfma_f32_16x16x32_bf16(a_, Bv1[S], acc1, 0, 0, 0); }

  LOADIT(0, 0); LOADIT(1, 1);
#pragma unroll
  for (int it = 0; it < 8; ++it) {
    if (it < 6) LOADIT(it + 2, (it + 2) % 3);
    PROCIT(it % 3);
  }
#undef LOADIT
#undef PROCIT

  // ss: lanes {l15, l15+16, l15+32, l15+48} hold partials for token l15
  ss += __shfl_xor(ss, 16); ss += __shfl_xor(ss, 32);
  if (kg == 0) ssp[wid][l15] = ss;
  // C layout: col(j) = l15, row(token) = kg*4+e
#pragma unroll
  for (int e = 0; e < 4; ++e) {
    int tok = kg * 4 + e;
    lgp[wid][tok][l15] = acc0[e];
    lgp[wid][tok][16 + l15] = acc1[e];
  }
  __syncthreads();

  // write 16 tok x 25 partials: pbuf[token*100 + kc*25 + j]
  for (int q = tid; q < 16 * 25; q += 512) {
    int tk = q / 25, j = q % 25;
    float v = 0.f;
    if (j < 24) {
#pragma unroll
      for (int w = 0; w < 8; ++w) v += lgp[w][tk][j];
    } else {
#pragma unroll
      for (int w = 0; w < 8; ++w) v += ssp[w][tk];
    }
    pbuf[(size_t)(t0 + tk) * 100 + kc * 25 + j] = v;
  }
}

// ------- Kernel 1b: finalize — sum 4 K-chunks, sigmoid/Sinkhorn, emit coeffs ---------
__global__ __launch_bounds__(256) void finalize_kernel(
    const float* __restrict__ pbuf, const float* __restrict__ bb,
    const float* __restrict__ apre_p, const float* __restrict__ apost_p,
    const float* __restrict__ ares_p, float* __restrict__ hpre,
    float* __restrict__ hpost, float* __restrict__ hres) {
  long t = (long)blockIdx.x * 256 + threadIdx.x;
  const float* pt = pbuf + (size_t)t * 100;
  float lg[25];
#pragma unroll
  for (int j = 0; j < 25; ++j)
    lg[j] = pt[j] + pt[25 + j] + pt[50 + j] + pt[75 + j];
  float r = rsqrtf(lg[24] / (float)Dn + 1e-6f);
  float apre = apre_p[0], apost = apost_p[0], ares = ares_p[0];
#pragma unroll
  for (int j = 0; j < NLg; ++j) lg[j] = r * lg[j] + bb[j];
#pragma unroll
  for (int j = 0; j < 4; ++j) hpre[t * 4 + j] = sigm(apre * lg[j]) + 1e-4f;
#pragma unroll
  for (int j = 0; j < 4; ++j) hpost[t * 4 + j] = 2.0f * sigm(apost * lg[4 + j]);
  float m[16];
#pragma unroll
  for (int q = 0; q < 16; ++q) m[q] = expf(ares * lg[8 + q]);
  for (int it = 0; it < TMAXn; ++it) {
#pragma unroll
    for (int o = 0; o < 4; ++o) {
      float rs = m[o*4] + m[o*4+1] + m[o*4+2] + m[o*4+3] + 1e-6f;
      m[o*4] /= rs; m[o*4+1] /= rs; m[o*4+2] /= rs; m[o*4+3] /= rs;
    }
#pragma unroll
    for (int i = 0; i < 4; ++i) {
      float cs = m[i] + m[4+i] + m[8+i] + m[12+i] + 1e-6f;
      m[i] /= cs; m[4+i] /= cs; m[8+i] /= cs; m[12+i] /= cs;
    }
  }
#pragma unroll
  for (int q = 0; q < 16; ++q) hres[t * 16 + q] = m[q];
}

// ------- Kernel 1c: x_in = sum_hc h_pre[hc]*x[hc,:] (bf16), one token per block -----
__global__ __launch_bounds__(256) void xin_kernel(
    const float* __restrict__ x, const float* __restrict__ hpre,
    unsigned int* __restrict__ xin) {
  long t = blockIdx.x;
  int tid = threadIdx.x;
  float h0 = hpre[t * 4 + 0], h1 = hpre[t * 4 + 1];
  float h2 = hpre[t * 4 + 2], h3 = hpre[t * 4 + 3];
  const float4* xt = (const float4*)(x + (size_t)t * Dn);
  uint2* xo = (uint2*)xin + (size_t)t * (Cn / 4);
#pragma unroll
  for (int it = 0; it < 2; ++it) {
    int c4 = it * 256 + tid;
    float4 v0 = xt[c4];
    float4 v1 = xt[c4 + 512];
    float4 v2 = xt[c4 + 1024];
    float4 v3 = xt[c4 + 1536];
    float sx = h0*v0.x + h1*v1.x + h2*v2.x + h3*v3.x;
    float sy = h0*v0.y + h1*v1.y + h2*v2.y + h3*v3.y;
    float sz = h0*v0.z + h1*v1.z + h2*v2.z + h3*v3.z;
    float sw = h0*v0.w + h1*v1.w + h2*v2.w + h3*v3.w;
    uint2 o; o.x = pk2(sx, sy); o.y = pk2(sz, sw);
    xo[c4] = o;
  }
}

// ---------------- Kernel 2: W (K x N, f32) -> Wt (N x K, bf16) ----------------
__global__ __launch_bounds__(256) void wtrans_kernel(const float* __restrict__ W,
                                                     unsigned short* __restrict__ Wt) {
  __shared__ float tile[64][65];
  int kb = blockIdx.y * 64, nb = blockIdx.x * 64;
  int tr = threadIdx.x >> 4;
  int tc = threadIdx.x & 15;
#pragma unroll
  for (int rr = 0; rr < 64; rr += 16) {
    float4 v = *(const float4*)&W[(size_t)(kb + tr + rr) * Cn + nb + tc * 4];
    tile[tr + rr][tc * 4 + 0] = v.x; tile[tr + rr][tc * 4 + 1] = v.y;
    tile[tr + rr][tc * 4 + 2] = v.z; tile[tr + rr][tc * 4 + 3] = v.w;
  }
  __syncthreads();
#pragma unroll
  for (int rr = 0; rr < 64; rr += 16) {
    int n = nb + tr + rr;
    uint2 o;
    o.x = pk2(tile[tc * 4 + 0][tr + rr], tile[tc * 4 + 1][tr + rr]);
    o.y = pk2(tile[tc * 4 + 2][tr + rr], tile[tc * 4 + 3][tr + rr]);
    *(uint2*)&Wt[(size_t)n * Cn + kb + tc * 4] = o;
  }
}

// ---------------- Kernel 3: bf16 MFMA GEMM (x_in @ W) + fused epilogue ----------------
#define BMt 128
#define BNt 128
#define BKt 32
#define GK Cn
__global__ __launch_bounds__(256) void gemm_ep_kernel(
    const unsigned short* __restrict__ xin, const unsigned short* __restrict__ Wt,
    const float* __restrict__ x, const float* __restrict__ Wb,
    const float* __restrict__ hpost, const float* __restrict__ hres,
    float* __restrict__ out) {
  __shared__ __align__(16) unsigned short As[BMt * BKt];
  __shared__ __align__(16) unsigned short Bs[BNt * BKt];
  int tid = threadIdx.x;
  int lane = tid & 63, wid = tid >> 6;
  int wr = wid >> 1, wc = wid & 1;
  int l15 = lane & 15, l4 = lane >> 4;
  int wg = blockIdx.x;
  wg = (wg & 7) * 64 + (wg >> 3);   // XCD swizzle, 512 % 8 == 0 bijective
  int bx = wg & 15, by = wg >> 4;

  f32x4 acc[4][4];
#pragma unroll
  for (int i = 0; i < 4; ++i)
#pragma unroll
    for (int j = 0; j < 4; ++j) acc[i][j] = {0.f, 0.f, 0.f, 0.f};

  const char* Ab = (const char*)xin + (size_t)by * BMt * GK * 2;
  const char* Bb = (const char*)Wt + (size_t)bx * BNt * GK * 2;
  int off0 = tid * 16, off1 = tid * 16 + 4096;
  int row0 = off0 >> 6, colb0 = off0 & 63;
  int row1 = off1 >> 6, colb1 = off1 & 63;

  for (int k0 = 0; k0 < GK; k0 += BKt) {
    gload_lds16(Ab + (size_t)row0 * (GK * 2) + k0 * 2 + colb0, (char*)As + off0);
    gload_lds16(Ab + (size_t)row1 * (GK * 2) + k0 * 2 + colb1, (char*)As + off1);
    gload_lds16(Bb + (size_t)row0 * (GK * 2) + k0 * 2 + colb0, (char*)Bs + off0);
    gload_lds16(Bb + (size_t)row1 * (GK * 2) + k0 * 2 + colb1, (char*)Bs + off1);
    __syncthreads();
    bf16x8 af[4], bfv[4];
#pragma unroll
    for (int fm = 0; fm < 4; ++fm)
      af[fm] = *(const bf16x8*)&As[(wr * 64 + fm * 16 + l15) * BKt + l4 * 8];
#pragma unroll
    for (int fn = 0; fn < 4; ++fn)
      bfv[fn] = *(const bf16x8*)&Bs[(wc * 64 + fn * 16 + l15) * BKt + l4 * 8];
#pragma unroll
    for (int fm = 0; fm < 4; ++fm)
#pragma unroll
      for (int fn = 0; fn < 4; ++fn)
        acc[fm][fn] = __builtin_amdgcn_mfma_f32_16x16x32_bf16(af[fm], bfv[fn], acc[fm][fn], 0, 0, 0);
    __syncthreads();
  }

  int m0 = by * BMt + wr * 64;
  int n0 = bx * BNt + wc * 64;
#pragma unroll
  for (int fm = 0; fm < 4; ++fm) {
#pragma unroll
    for (int e = 0; e < 4; ++e) {
      int t = m0 + fm * 16 + l4 * 4 + e;
      const float* hr = hres + (size_t)t * 16;
      const float* hq = hpost + (size_t)t * 4;
      const float* xt = x + (size_t)t * Dn;
      float* ot = out + (size_t)t * Dn;
      float hr_[16], hq_[4];
#pragma unroll
      for (int q = 0; q < 16; ++q) hr_[q] = hr[q];
#pragma unroll
      for (int q = 0; q < 4; ++q) hq_[q] = hq[q];
#pragma unroll
      for (int fn = 0; fn < 4; ++fn) {
        int c = n0 + fn * 16 + l15;
        float f = acc[fm][fn][e] + Wb[c];
        float x0 = xt[c], x1 = xt[Cn + c], x2 = xt[2 * Cn + c], x3 = xt[3 * Cn + c];
#pragma unroll
        for (int o = 0; o < 4; ++o) {
          ot[(size_t)o * Cn + c] =
              hq_[o] * f + hr_[o*4+0] * x0 + hr_[o*4+1] * x1 + hr_[o*4+2] * x2 + hr_[o*4+3] * x3;
        }
      }
    }
  }
}

extern "C" void kernel_launch(void* const* d_in, const int* in_sizes, int n_in,
                              void* d_out, int out_size, void* d_ws, size_t ws_size,
                              hipStream_t stream) {
  const float* x     = (const float*)d_in[0];
  const float* phi   = (const float*)d_in[1];
  const float* b     = (const float*)d_in[2];
  const float* apre  = (const float*)d_in[3];
  const float* apost = (const float*)d_in[4];
  const float* ares  = (const float*)d_in[5];
  const float* W     = (const float*)d_in[6];
  const float* Wb    = (const float*)d_in[7];
  float* out = (float*)d_out;

  int NT = in_sizes[0] / Dn;   // 4096 tokens
  char* ws = (char*)d_ws;
  size_t off = 0;
  unsigned int*   xin  = (unsigned int*)(ws + off);   off += (size_t)NT * Cn * 2;   // 16 MB
  unsigned short* Wt   = (unsigned short*)(ws + off); off += (size_t)Cn * Cn * 2;   // 8 MB
  float* hpre  = (float*)(ws + off); off += (size_t)NT * 4 * 4;
  float* hpost = (float*)(ws + off); off += (size_t)NT * 4 * 4;
  float* hres  = (float*)(ws + off); off += (size_t)NT * 16 * 4;
  unsigned short* phiB = (unsigned short*)(ws + off); off += (size_t)Dn * 32 * 2;   // 512 KB
  float* pbuf  = (float*)(ws + off); off += (size_t)NT * 100 * 4;                   // 1.6 MB

  hipLaunchKernelGGL(phib_kernel, dim3(Dn / 32), dim3(128), 0, stream, phi, phiB);
  hipLaunchKernelGGL(logits_kernel, dim3((NT / 16) * 4), dim3(512), 0, stream,
                     x, phiB, pbuf);
  hipLaunchKernelGGL(finalize_kernel, dim3(NT / 256), dim3(256), 0, stream,
                     pbuf, b, apre, apost, ares, hpre, hpost, hres);
  hipLaunchKernelGGL(xin_kernel, dim3(NT), dim3(256), 0, stream, x, hpre, xin);
  hipLaunchKernelGGL(wtrans_kernel, dim3(Cn / 64, Cn / 64), dim3(256), 0, stream, W, Wt);
  hipLaunchKernelGGL(gemm_ep_kernel, dim3((Cn / BNt) * (NT / BMt)), dim3(256), 0, stream,
                     (const unsigned short*)xin, Wt, x, Wb, hpost, hres, out);
}